// Round 6
// baseline (293.780 us; speedup 1.0000x reference)
//
#include <hip/hip_runtime.h>
#include <hip/hip_bf16.h>
#include <stdint.h>

#define H_DIM 1024
#define S_DIM 4096
#define B_DIM 4

typedef __bf16 bf16x8 __attribute__((ext_vector_type(8)));
typedef float f32x4 __attribute__((ext_vector_type(4)));
typedef unsigned short u16x4 __attribute__((ext_vector_type(4)));
typedef unsigned short u16x8 __attribute__((ext_vector_type(8)));

__device__ __forceinline__ unsigned short f2bf(float f) {
    union { float f; uint32_t u; } v; v.f = f;
    uint32_t u = v.u;
    uint32_t r = (u + 0x7FFFu + ((u >> 16) & 1u)) >> 16;  // round-to-nearest-even
    return (unsigned short)r;
}
__device__ __forceinline__ float bf2f(unsigned short u) {
    union { uint32_t u; float f; } v; v.u = (uint32_t)u << 16; return v.f;
}

// Raw barrier (no implicit vmcnt/lgkmcnt drain).
__device__ __forceinline__ void wg_barrier() {
    asm volatile("s_barrier" ::: "memory");
}

// Inline-asm LDS read: opaque to LDS-DMA alias tracking (compiler cannot
// insert vmcnt(0) drains). Safety: DMA landing is guaranteed by the
// gate-own-vmcnt -> s_barrier pair BEFORE the read; read->MFMA ordering by
// lgkmcnt(0) + sched_barrier(0) (rule #18).
template <int IMM>
__device__ __forceinline__ bf16x8 ds_read_b128_imm(unsigned addr) {
    bf16x8 r;
    asm volatile("ds_read_b128 %0, %1 offset:%2"
                 : "=v"(r) : "v"(addr), "i"(IMM));
    return r;
}

// X[b][s][h] fp32 -> Xb[b][s][h] bf16  and  XT[b][h][s] bf16 (vectorized)
__global__ __launch_bounds__(256)
void cast_x_kernel(const float* __restrict__ X,
                   unsigned short* __restrict__ Xb,
                   unsigned short* __restrict__ XT) {
    __shared__ float tile[64][65];
    const int b  = blockIdx.z;
    const int h0 = blockIdx.x * 64;
    const int s0 = blockIdx.y * 64;
    const int tx = threadIdx.x;   // 0..15
    const int ty = threadIdx.y;   // 0..15
#pragma unroll
    for (int j = 0; j < 4; ++j) {
        int s = ty + 16 * j;
        f32x4 v = *(const f32x4*)&X[((size_t)b * S_DIM + s0 + s) * H_DIM + h0 + tx * 4];
        u16x4 o;
#pragma unroll
        for (int k = 0; k < 4; ++k) {
            tile[s][tx * 4 + k] = v[k];
            o[k] = f2bf(v[k]);
        }
        *(u16x4*)&Xb[((size_t)b * S_DIM + s0 + s) * H_DIM + h0 + tx * 4] = o;
    }
    __syncthreads();
#pragma unroll
    for (int j = 0; j < 4; ++j) {
        int hh = ty + 16 * j;
        u16x4 o;
#pragma unroll
        for (int k = 0; k < 4; ++k)
            o[k] = f2bf(tile[tx * 4 + k][hh]);
        *(u16x4*)&XT[((size_t)b * H_DIM + h0 + hh) * S_DIM + s0 + tx * 4] = o;
    }
}

// W[o][h'] fp32 -> WT[h'][o] bf16 (small: 4 MB read)
__global__ void cast_w_kernel(const float* __restrict__ W,
                              unsigned short* __restrict__ WT) {
    __shared__ float tile[32][33];
    const int b0 = blockIdx.x * 32;
    const int o0 = blockIdx.y * 32;
    const int tx = threadIdx.x;
    const int ty = threadIdx.y;
#pragma unroll
    for (int i = 0; i < 4; ++i) {
        int o = ty + 8 * i;
        tile[o][tx] = W[(size_t)(o0 + o) * H_DIM + b0 + tx];
    }
    __syncthreads();
#pragma unroll
    for (int i = 0; i < 4; ++i) {
        int bb = ty + 8 * i;
        WT[(size_t)(b0 + bb) * H_DIM + o0 + tx] = f2bf(tile[tx][bb]);
    }
}

// Sum NSPLIT bf16 partials -> bf16. 16B/lane both directions.
template <int NSPLIT>
__global__ void reduce_cast_u16_kernel(const unsigned short* __restrict__ P,
                                       unsigned short* __restrict__ Out,
                                       size_t sSplit) {
    size_t i = ((size_t)blockIdx.x * blockDim.x + threadIdx.x) * 8;
    float s[8] = {0.f, 0.f, 0.f, 0.f, 0.f, 0.f, 0.f, 0.f};
#pragma unroll
    for (int sp = 0; sp < NSPLIT; ++sp) {
        u16x8 u = *(const u16x8*)&P[(size_t)sp * sSplit + i];
#pragma unroll
        for (int k = 0; k < 8; ++k) s[k] += bf2f(u[k]);
    }
    u16x8 o;
#pragma unroll
    for (int k = 0; k < 8; ++k) o[k] = f2bf(s[k]);
    *(u16x8*)&Out[i] = o;
}

// ============================================================================
// R6: TLP-first GEMM. C[M,N] = A[M,K] @ Bt[N,K]^T (bf16 in, fp32 acc, OutT out)
//
// R2/R3/R5 post-mortem: three different intra-block schedules all pinned at
// ~22% MfmaUtil with 1 block/CU — every pipe 22-36% busy, pure latency
// serialization with nothing to fill the gaps. m97 (128^2, dumb schedule,
// ~3 blocks/CU) hits 874 TF via cross-block TLP (m114). R6 goes there, while
// keeping R5's proven counted-vmcnt gating discipline.
//
// Geometry: 128x128 tile, 256 threads = 4 waves (2M x 2N), wave-tile 64x64 =
// 4x4 frags of v_mfma_f32_16x16x32_bf16 (acc 64 VGPR). K-tile = 32.
// LDS: THREE buffers x (A 8KB + B 8KB) = 49152 B, fragment-major
// [k8(4)][row(128)][8] per operand (conflict-free ds_read_b128, linear
// global_load_lds dest). __launch_bounds__(256,3): 3 blocks/CU = 12 waves/CU.
//
// Per body n (steady state):
//   gate: vmcnt(4)  [own tile-n loads (oldest 4) landed; tile n+1's 4 stay
//                    in flight; tile n+2 not yet issued]   (tail: vmcnt(0))
//   s_barrier       -> collectively: tile n resident in buf n%3
//   stage tile n+2 into buf (n+2)%3   [WAR-safe: that buffer's last reader
//     was tile n-1; every wave's tile-(n-1) reads returned before its own
//     lgkmcnt(0), which precedes its barrier arrival]
//   8x ds_read_b128 (av0-3, bv0-3); lgkmcnt(0)+sched_barrier; 16x MFMA
// Prefetch distance = 2 bodies (~covers L2 и most HBM latency); stalls that
// remain are hidden by the other 2 resident blocks.
// Requires T = Ksub/32 >= 2, M,N multiples of 128.
// ============================================================================
template <typename OutT, int NSPLIT, bool SWAPXY>
__global__ __launch_bounds__(256, 3)
void gemm_t3_kernel(const unsigned short* __restrict__ A,
                    const unsigned short* __restrict__ Bt,
                    OutT* __restrict__ C,
                    int K, int lda, int ldb, int ldc,
                    size_t sA, size_t sB, size_t sC, size_t sSplit) {
    extern __shared__ char smem_raw[];
    // stage: [buf(3)][A 8KB | B 8KB] = 49152 B; epi overlays post-__syncthreads
    // (float[4][1088] = 17408 B).

    const int tid  = threadIdx.x;
    const int w    = tid >> 6;       // 0..3
    const int lane = tid & 63;
    const int wm   = w & 1;          // M half: rows wm*64
    const int wn   = w >> 1;         // N half: cols wn*64
    const int q    = lane >> 4;      // 0..3 (k8)
    const int col  = lane & 15;

    int tileM, tileN;
    if constexpr (SWAPXY) {
        tileM = blockIdx.x * 128;
        tileN = blockIdx.y * 128;
    } else {
        tileN = blockIdx.x * 128;
        tileM = blockIdx.y * 128;
    }
    const int bz   = blockIdx.z / NSPLIT;
    const int sp   = blockIdx.z % NSPLIT;
    const int Ksub = K / NSPLIT;
    const int T    = Ksub >> 5;      // K-tiles of 32 (>= 2)

    const unsigned short* Ab = A + sA * bz + (size_t)sp * Ksub;
    const unsigned short* Bb = Bt + sB * bz + (size_t)sp * Ksub;

    auto lds3 = (__attribute__((address_space(3))) char*)&smem_raw[0];
    const unsigned ldsBase = (unsigned)(size_t)lds3;

    // fragment read bases (buf 0): A byte = q*2048 + (wm*64 + mf*16 + col)*16
    const unsigned aBase = ldsBase + (unsigned)(q * 2048 + (wm * 64 + col) * 16);
    const unsigned bBase = ldsBase + 8192u + (unsigned)(q * 2048 + (wn * 64 + col) * 16);

    // staging chunks: c = 2w+j -> k8 = c>>1 (0..3), r64 = c&1; 1 KB per load.
    const unsigned short* pA[2];
    const unsigned short* pB[2];
    unsigned dstOf[2];
#pragma unroll
    for (int j = 0; j < 2; ++j) {
        int c = 2 * w + j, k8 = c >> 1, r64 = c & 1;
        pA[j] = Ab + (size_t)(tileM + r64 * 64 + lane) * lda + k8 * 8;
        pB[j] = Bb + (size_t)(tileN + r64 * 64 + lane) * ldb + k8 * 8;
        dstOf[j] = (unsigned)((k8 * 128 + r64 * 64) * 16);
    }
    // stage K-tile tgt into buffer buf (4 loads/thread: A j0,j1, B j0,j1)
    auto stage = [&](int tgt, int buf) {
        unsigned bo = (unsigned)buf * 16384u;
#pragma unroll
        for (int j = 0; j < 2; ++j)
            __builtin_amdgcn_global_load_lds(
                (const __attribute__((address_space(1))) void*)(pA[j] + tgt * 32),
                (__attribute__((address_space(3))) void*)(lds3 + bo + dstOf[j]),
                16, 0, 0);
#pragma unroll
        for (int j = 0; j < 2; ++j)
            __builtin_amdgcn_global_load_lds(
                (const __attribute__((address_space(1))) void*)(pB[j] + tgt * 32),
                (__attribute__((address_space(3))) void*)(lds3 + bo + 8192u + dstOf[j]),
                16, 0, 0);
    };

    f32x4 acc[4][4];
#pragma unroll
    for (int r = 0; r < 4; ++r)
#pragma unroll
        for (int c = 0; c < 4; ++c)
            acc[r][c] = (f32x4){0.f, 0.f, 0.f, 0.f};

    // prologue: tiles 0,1 into bufs 0,1 (8 loads/thread)
    stage(0, 0);
    stage(1, 1);

    int buf = 0;          // buffer holding tile n
    int nbuf = 2;         // buffer for tile n+2
    for (int n = 0; n < T; ++n) {
        // own tile-n loads landed; tile n+1's 4 loads stay in flight
        if (n + 1 < T) asm volatile("s_waitcnt vmcnt(4)" ::: "memory");
        else           asm volatile("s_waitcnt vmcnt(0)" ::: "memory");
        wg_barrier();

        if (n + 2 < T) stage(n + 2, nbuf);

        const unsigned aAddr = aBase + (unsigned)(buf * 16384);
        const unsigned bAddr = bBase + (unsigned)(buf * 16384);
        bf16x8 av[4], bv[4];
        av[0] = ds_read_b128_imm<0>(aAddr);
        av[1] = ds_read_b128_imm<256>(aAddr);
        av[2] = ds_read_b128_imm<512>(aAddr);
        av[3] = ds_read_b128_imm<768>(aAddr);
        bv[0] = ds_read_b128_imm<0>(bAddr);
        bv[1] = ds_read_b128_imm<256>(bAddr);
        bv[2] = ds_read_b128_imm<512>(bAddr);
        bv[3] = ds_read_b128_imm<768>(bAddr);
        asm volatile("s_waitcnt lgkmcnt(0)" ::: "memory");
        __builtin_amdgcn_sched_barrier(0);
#pragma unroll
        for (int mf = 0; mf < 4; ++mf)
#pragma unroll
            for (int nf = 0; nf < 4; ++nf)
                acc[mf][nf] = __builtin_amdgcn_mfma_f32_16x16x32_bf16(
                    av[mf], bv[nf], acc[mf][nf], 0, 0, 0);

        buf  = (buf == 2)  ? 0 : buf + 1;
        nbuf = (nbuf == 2) ? 0 : nbuf + 1;
    }

    // epilogue: per-wave LDS transpose (stride 68 floats), coalesced stores.
    OutT* Cb = C + sC * bz + sSplit * sp;
    __syncthreads();   // all waves done with stage region before epi overlay
    float* lws = (float*)(smem_raw) + (size_t)w * 1088;
    const int lr = lane >> 4;
    const int lc = lane & 15;
#pragma unroll
    for (int mf = 0; mf < 4; ++mf) {
#pragma unroll
        for (int nf = 0; nf < 4; ++nf)
#pragma unroll
            for (int v = 0; v < 4; ++v)
                lws[(q * 4 + v) * 68 + nf * 16 + col] = acc[mf][nf][v];
#pragma unroll
        for (int p = 0; p < 4; ++p) {
            f32x4 t = *(const f32x4*)&lws[(p * 4 + lr) * 68 + lc * 4];
            int row  = tileM + wm * 64 + mf * 16 + p * 4 + lr;
            int colg = tileN + wn * 64 + lc * 4;
            if constexpr (sizeof(OutT) == 2) {
                u16x4 u;
                u[0] = f2bf(t[0]); u[1] = f2bf(t[1]);
                u[2] = f2bf(t[2]); u[3] = f2bf(t[3]);
                *(u16x4*)&Cb[(size_t)row * ldc + colg] = u;
            } else {
                *(f32x4*)&Cb[(size_t)row * ldc + colg] = t;
            }
        }
        // per-wave epi slice is private; no inter-mf barrier needed
    }
}

extern "C" void kernel_launch(void* const* d_in, const int* in_sizes, int n_in,
                              void* d_out, int out_size, void* d_ws, size_t ws_size,
                              hipStream_t stream) {
    const float* X = (const float*)d_in[0];   // [4,4096,1024]
    const float* W = (const float*)d_in[1];   // [1024,1024]
    float* out = (float*)d_out;               // [4,4096,1024] fp32

    char* ws = (char*)d_ws;
    unsigned short* Xb = (unsigned short*)(ws);              // 33,554,432  [b][s][h]
    unsigned short* XT = (unsigned short*)(ws + 33554432);   // 33,554,432  [b][h][s]
    unsigned short* WT = (unsigned short*)(ws + 67108864);   //  2,097,152  [h'][o]
    unsigned short* G  = (unsigned short*)(ws + 69206016);   //  8,388,608  [b][o][h]
    unsigned short* MT = (unsigned short*)(ws + 77594624);   //  8,388,608  [b][h''][h]
    // Scratch (reused serially): Gpart then MTpart, each [sp(4)][b][1024][1024]
    unsigned short* Gpart  = (unsigned short*)(ws + 85983232); // 16,777,216
    unsigned short* MTpart = (unsigned short*)(ws + 85983232); // 16,777,216
    // high-water: 102,760,448 bytes < 153,092,096 proven available

    const size_t sBH = (size_t)B_DIM * H_DIM * H_DIM;

    // 1) casts + transposes
    cast_x_kernel<<<dim3(H_DIM / 64, S_DIM / 64, B_DIM), dim3(16, 16), 0, stream>>>(X, Xb, XT);
    cast_w_kernel<<<dim3(H_DIM / 32, H_DIM / 32, 1), dim3(32, 8), 0, stream>>>(W, WT);

    // 2) G_b = XT_b @ XT_b^T, full symmetric, split-K=4 (Ksub=1024, T=32).
    //    grid (8,8,16) = 1024 blocks = 4 per CU (3 resident + 1 chained).
    gemm_t3_kernel<unsigned short, 4, false><<<dim3(8, 8, B_DIM * 4), 256, 49152, stream>>>(
        XT, XT, Gpart, S_DIM, S_DIM, S_DIM, H_DIM,
        (size_t)H_DIM * S_DIM, (size_t)H_DIM * S_DIM, (size_t)H_DIM * H_DIM, sBH);
    reduce_cast_u16_kernel<4><<<dim3(sBH / 8 / 256), 256, 0, stream>>>(Gpart, G, sBH);

    // 3) MT_b = G_b @ WT^T, split-K=4 (Ksub=256, T=8), 1024 blocks
    gemm_t3_kernel<unsigned short, 4, false><<<dim3(8, 8, B_DIM * 4), 256, 49152, stream>>>(
        G, WT, MTpart, H_DIM, H_DIM, H_DIM, H_DIM,
        (size_t)H_DIM * H_DIM, (size_t)0, (size_t)H_DIM * H_DIM, sBH);
    reduce_cast_u16_kernel<4><<<dim3(sBH / 8 / 256), 256, 0, stream>>>(MTpart, MT, sBH);

    // 4) att_b = Xb_b @ MT_b^T  [4096x1024], K=1024 (T=32), fp32 out.
    //    SWAPXY: x = M-tile (32), y = N-tile (8); 1024 blocks.
    gemm_t3_kernel<float, 1, true><<<dim3(S_DIM / 128, H_DIM / 128, B_DIM), 256, 49152, stream>>>(
        Xb, MT, out, H_DIM, H_DIM, H_DIM, H_DIM,
        (size_t)S_DIM * H_DIM, (size_t)H_DIM * H_DIM, (size_t)S_DIM * H_DIM, 0);
}

// Round 7
// 253.954 us; speedup vs baseline: 1.1568x; 1.1568x over previous
//
#include <hip/hip_runtime.h>
#include <hip/hip_bf16.h>
#include <stdint.h>

#define H_DIM 1024
#define S_DIM 4096
#define B_DIM 4

typedef __bf16 bf16x8 __attribute__((ext_vector_type(8)));
typedef float f32x4 __attribute__((ext_vector_type(4)));
typedef unsigned short u16x4 __attribute__((ext_vector_type(4)));
typedef unsigned short u16x8 __attribute__((ext_vector_type(8)));

__device__ __forceinline__ unsigned short f2bf(float f) {
    union { float f; uint32_t u; } v; v.f = f;
    uint32_t u = v.u;
    uint32_t r = (u + 0x7FFFu + ((u >> 16) & 1u)) >> 16;  // round-to-nearest-even
    return (unsigned short)r;
}
__device__ __forceinline__ float bf2f(unsigned short u) {
    union { uint32_t u; float f; } v; v.u = (uint32_t)u << 16; return v.f;
}

// R7 FIX: all K-loop sync is now CLOBBER-FREE.
// Previous rounds used asm volatile(... ::: "memory") for barriers and
// waitcnt gates. A "memory" clobber makes LLVM's memory legalizer treat the
// asm as touching all memory and conservatively insert s_waitcnt vmcnt(0)
// before it while global_load_lds ops are outstanding — silently turning
// EVERY schedule (R0-R6) into "full drain per tile", which is exactly why
// five different choreographies all measured ~22% MfmaUtil.
// The m201-proven pattern: __builtin_amdgcn_s_barrier() (no drain) +
// clobber-free volatile asm s_waitcnt + sched_barrier(0) pinning (rule #18).
__device__ __forceinline__ void gate_vmcnt4() {
    __builtin_amdgcn_sched_barrier(0);
    asm volatile("s_waitcnt vmcnt(4)");
    __builtin_amdgcn_sched_barrier(0);
}
__device__ __forceinline__ void gate_vmcnt0() {
    __builtin_amdgcn_sched_barrier(0);
    asm volatile("s_waitcnt vmcnt(0)");
    __builtin_amdgcn_sched_barrier(0);
}
__device__ __forceinline__ void gate_lgkm0() {
    asm volatile("s_waitcnt lgkmcnt(0)");
    __builtin_amdgcn_sched_barrier(0);   // rule #18: stop MFMAs hoisting above
}

// Inline-asm LDS read: opaque to LDS-DMA alias tracking (compiler cannot
// insert vmcnt(0) drains on its behalf). Safety: DMA landing guaranteed by
// gate-own-vmcnt -> s_barrier BEFORE the read; read->MFMA ordering by
// gate_lgkm0 (volatile asms keep mutual program order).
template <int IMM>
__device__ __forceinline__ bf16x8 ds_read_b128_imm(unsigned addr) {
    bf16x8 r;
    asm volatile("ds_read_b128 %0, %1 offset:%2"
                 : "=v"(r) : "v"(addr), "i"(IMM));
    return r;
}

// X[b][s][h] fp32 -> Xb[b][s][h] bf16  and  XT[b][h][s] bf16 (vectorized)
__global__ __launch_bounds__(256)
void cast_x_kernel(const float* __restrict__ X,
                   unsigned short* __restrict__ Xb,
                   unsigned short* __restrict__ XT) {
    __shared__ float tile[64][65];
    const int b  = blockIdx.z;
    const int h0 = blockIdx.x * 64;
    const int s0 = blockIdx.y * 64;
    const int tx = threadIdx.x;   // 0..15
    const int ty = threadIdx.y;   // 0..15
#pragma unroll
    for (int j = 0; j < 4; ++j) {
        int s = ty + 16 * j;
        f32x4 v = *(const f32x4*)&X[((size_t)b * S_DIM + s0 + s) * H_DIM + h0 + tx * 4];
        u16x4 o;
#pragma unroll
        for (int k = 0; k < 4; ++k) {
            tile[s][tx * 4 + k] = v[k];
            o[k] = f2bf(v[k]);
        }
        *(u16x4*)&Xb[((size_t)b * S_DIM + s0 + s) * H_DIM + h0 + tx * 4] = o;
    }
    __syncthreads();
#pragma unroll
    for (int j = 0; j < 4; ++j) {
        int hh = ty + 16 * j;
        u16x4 o;
#pragma unroll
        for (int k = 0; k < 4; ++k)
            o[k] = f2bf(tile[tx * 4 + k][hh]);
        *(u16x4*)&XT[((size_t)b * H_DIM + h0 + hh) * S_DIM + s0 + tx * 4] = o;
    }
}

// W[o][h'] fp32 -> WT[h'][o] bf16 (small: 4 MB read)
__global__ void cast_w_kernel(const float* __restrict__ W,
                              unsigned short* __restrict__ WT) {
    __shared__ float tile[32][33];
    const int b0 = blockIdx.x * 32;
    const int o0 = blockIdx.y * 32;
    const int tx = threadIdx.x;
    const int ty = threadIdx.y;
#pragma unroll
    for (int i = 0; i < 4; ++i) {
        int o = ty + 8 * i;
        tile[o][tx] = W[(size_t)(o0 + o) * H_DIM + b0 + tx];
    }
    __syncthreads();
#pragma unroll
    for (int i = 0; i < 4; ++i) {
        int bb = ty + 8 * i;
        WT[(size_t)(b0 + bb) * H_DIM + o0 + tx] = f2bf(tile[tx][bb]);
    }
}

// Sum NSPLIT bf16 partials -> bf16. 16B/lane both directions.
template <int NSPLIT>
__global__ void reduce_cast_u16_kernel(const unsigned short* __restrict__ P,
                                       unsigned short* __restrict__ Out,
                                       size_t sSplit) {
    size_t i = ((size_t)blockIdx.x * blockDim.x + threadIdx.x) * 8;
    float s[8] = {0.f, 0.f, 0.f, 0.f, 0.f, 0.f, 0.f, 0.f};
#pragma unroll
    for (int sp = 0; sp < NSPLIT; ++sp) {
        u16x8 u = *(const u16x8*)&P[(size_t)sp * sSplit + i];
#pragma unroll
        for (int k = 0; k < 8; ++k) s[k] += bf2f(u[k]);
    }
    u16x8 o;
#pragma unroll
    for (int k = 0; k < 8; ++k) o[k] = f2bf(s[k]);
    *(u16x8*)&Out[i] = o;
}

// ============================================================================
// R7: R5's 4-phase paced GEMM with clobber-free sync (see note at gate_*).
// C[M,N] = A[M,K] @ Bt[N,K]^T  (bf16 in, fp32 accum, OutT out)
// Geometry: 256x256 tile, 512 threads = 8 waves (2M x 4N), wave-tile 128x64
// = 8x4 frags of v_mfma_f32_16x16x32_bf16. BK=64. LDS: 2 buffers x
// (A 32KB + B 32KB) = 131072 B, fragment-major [k8(8)][row(256)][8]
// (conflict-free ds_read_b128, linear global_load_lds dest).
// Half h of tile = k8 h*4..h*4+3 (kc=h), 16 KB per operand, 2 loads/thread.
//
// Per K-tile n (stages issue halves of tile n+1 into buf (n+1)&1):
//   G0: vmcnt(4) [own A(n,0),B(n,0) landed; A(n,1),B(n,1) in flight]; barrier
//   P0: 8 ds_reads kc0 | stage A(n+1,0) | lgkm0 | prio1 16MFMA prio0
//   P1: 4 ds_reads kc0-hi | stage B(n+1,0) | lgkm0 | prio1 16MFMA prio0
//   G1: vmcnt(pf?4:0) [A(n,1),B(n,1) landed]; barrier
//   P2: 8 ds_reads kc1 | stage A(n+1,1) | ... 16MFMA
//   P3: 4 ds_reads kc1-hi | stage B(n+1,1) | ... 16MFMA
// Gate audit (2 loads/stage-unit, queue oldest->newest): G0 entry = 8
// outstanding, drains oldest 4 = A(n,0),B(n,0); G1 entry = 8, drains
// A(n,1),B(n,1). vmcnt never 0 until the final tile's G1.
// WAR safety: restage of buf (n+1)&1 happens after G0(n)/G1(n) barriers;
// every wave's tile-(n-1) reads returned before its own lgkm0, which
// precedes its barrier arrival. Works for any T >= 1. M,N multiples of 256.
// ============================================================================
template <typename OutT, int NSPLIT>
__global__ __launch_bounds__(512, 2)
void gemm_p7_kernel(const unsigned short* __restrict__ A,
                    const unsigned short* __restrict__ Bt,
                    OutT* __restrict__ C,
                    int K, int lda, int ldb, int ldc,
                    size_t sA, size_t sB, size_t sC, size_t sSplit) {
    extern __shared__ char smem_raw[];
    // stage: [buf(2)][A 32KB | B 32KB] = 131072 B; epi overlays post-sync.

    const int tid  = threadIdx.x;
    const int w    = tid >> 6;       // 0..7
    const int lane = tid & 63;
    const int wm   = w & 1;          // M half: rows wm*128
    const int wn   = w >> 1;         // N quarter: cols wn*64
    const int q    = lane >> 4;      // 0..3
    const int col  = lane & 15;

    const int tileM = blockIdx.x * 256;
    const int tileN = blockIdx.y * 256;
    const int bz   = blockIdx.z / NSPLIT;
    const int sp   = blockIdx.z % NSPLIT;
    const int Ksub = K / NSPLIT;
    const int T    = Ksub >> 6;      // K-tiles of 64

    const unsigned short* Ab = A + sA * bz + (size_t)sp * Ksub;
    const unsigned short* Bb = Bt + sB * bz + (size_t)sp * Ksub;

    auto lds3 = (__attribute__((address_space(3))) char*)&smem_raw[0];
    const unsigned ldsBase = (unsigned)(size_t)lds3;

    // fragment read bases (buf 0). A byte addr for (kc,mf):
    //   buf*65536 + kc*16384 + q*4096 + (wm*128 + mf*16 + col)*16
    const unsigned aBase = ldsBase + (unsigned)(q * 4096 + (wm * 128 + col) * 16);
    const unsigned bBase = ldsBase + 32768u + (unsigned)(q * 4096 + (wn * 64 + col) * 16);

    // staging chunks: c = 2w+j -> k8rel = c>>2 (0..3), r64 = c&3; 1 KB/load.
    const unsigned short* pA[2];
    const unsigned short* pB[2];
    unsigned dstA[2];
#pragma unroll
    for (int j = 0; j < 2; ++j) {
        int c = 2 * w + j, k8r = c >> 2, r64 = c & 3;
        pA[j] = Ab + (size_t)(tileM + r64 * 64 + lane) * lda + k8r * 8;
        pB[j] = Bb + (size_t)(tileN + r64 * 64 + lane) * ldb + k8r * 8;
        dstA[j] = (unsigned)(k8r * 4096 + r64 * 1024);
    }
    // stage half h (kc=h) of A/B for target tile tgt into buf tgt&1
    auto stageA = [&](int tgt, int h) {
#pragma unroll
        for (int j = 0; j < 2; ++j)
            __builtin_amdgcn_global_load_lds(
                (const __attribute__((address_space(1))) void*)(pA[j] + tgt * 64 + h * 32),
                (__attribute__((address_space(3))) void*)(lds3 + ((unsigned)(tgt & 1) * 65536u + dstA[j] + (unsigned)h * 16384u)),
                16, 0, 0);
    };
    auto stageB = [&](int tgt, int h) {
#pragma unroll
        for (int j = 0; j < 2; ++j)
            __builtin_amdgcn_global_load_lds(
                (const __attribute__((address_space(1))) void*)(pB[j] + tgt * 64 + h * 32),
                (__attribute__((address_space(3))) void*)(lds3 + ((unsigned)(tgt & 1) * 65536u + 32768u + dstA[j] + (unsigned)h * 16384u)),
                16, 0, 0);
    };

    f32x4 acc[8][4];
#pragma unroll
    for (int r = 0; r < 8; ++r)
#pragma unroll
        for (int c = 0; c < 4; ++c)
            acc[r][c] = (f32x4){0.f, 0.f, 0.f, 0.f};

    // prologue: tile 0's 4 halves, consumption order A0,B0,A1,B1
    stageA(0, 0); stageB(0, 0); stageA(0, 1); stageB(0, 1);

    for (int n = 0; n < T; ++n) {
        const unsigned aAddr = aBase + (unsigned)((n & 1) << 16);
        const unsigned bAddr = bBase + (unsigned)((n & 1) << 16);
        const bool pf = (n + 1 < T);
        bf16x8 av[4], bv[4];

        // ===== G0: A(n,0),B(n,0) landed (own); barrier makes it collective ===
        gate_vmcnt4();
        __builtin_amdgcn_s_barrier();

        // ---- P0: kc=0, mf 0..3 ----
        av[0] = ds_read_b128_imm<0>(aAddr);
        av[1] = ds_read_b128_imm<256>(aAddr);
        av[2] = ds_read_b128_imm<512>(aAddr);
        av[3] = ds_read_b128_imm<768>(aAddr);
        bv[0] = ds_read_b128_imm<0>(bAddr);
        bv[1] = ds_read_b128_imm<256>(bAddr);
        bv[2] = ds_read_b128_imm<512>(bAddr);
        bv[3] = ds_read_b128_imm<768>(bAddr);
        if (pf) stageA(n + 1, 0);
        gate_lgkm0();
        __builtin_amdgcn_s_setprio(1);
#pragma unroll
        for (int mf = 0; mf < 4; ++mf)
#pragma unroll
            for (int nf = 0; nf < 4; ++nf)
                acc[mf][nf] = __builtin_amdgcn_mfma_f32_16x16x32_bf16(
                    av[mf], bv[nf], acc[mf][nf], 0, 0, 0);
        __builtin_amdgcn_s_setprio(0);

        // ---- P1: kc=0, mf 4..7 (bv reused) ----
        av[0] = ds_read_b128_imm<1024>(aAddr);
        av[1] = ds_read_b128_imm<1280>(aAddr);
        av[2] = ds_read_b128_imm<1536>(aAddr);
        av[3] = ds_read_b128_imm<1792>(aAddr);
        if (pf) stageB(n + 1, 0);
        gate_lgkm0();
        __builtin_amdgcn_s_setprio(1);
#pragma unroll
        for (int mf = 0; mf < 4; ++mf)
#pragma unroll
            for (int nf = 0; nf < 4; ++nf)
                acc[4 + mf][nf] = __builtin_amdgcn_mfma_f32_16x16x32_bf16(
                    av[mf], bv[nf], acc[4 + mf][nf], 0, 0, 0);
        __builtin_amdgcn_s_setprio(0);

        // ===== G1: A(n,1),B(n,1) landed; n+1's first halves stay in flight ===
        if (pf) gate_vmcnt4();
        else    gate_vmcnt0();
        __builtin_amdgcn_s_barrier();

        // ---- P2: kc=1, mf 0..3, new bv ----
        av[0] = ds_read_b128_imm<16384 + 0>(aAddr);
        av[1] = ds_read_b128_imm<16384 + 256>(aAddr);
        av[2] = ds_read_b128_imm<16384 + 512>(aAddr);
        av[3] = ds_read_b128_imm<16384 + 768>(aAddr);
        bv[0] = ds_read_b128_imm<16384 + 0>(bAddr);
        bv[1] = ds_read_b128_imm<16384 + 256>(bAddr);
        bv[2] = ds_read_b128_imm<16384 + 512>(bAddr);
        bv[3] = ds_read_b128_imm<16384 + 768>(bAddr);
        if (pf) stageA(n + 1, 1);
        gate_lgkm0();
        __builtin_amdgcn_s_setprio(1);
#pragma unroll
        for (int mf = 0; mf < 4; ++mf)
#pragma unroll
            for (int nf = 0; nf < 4; ++nf)
                acc[mf][nf] = __builtin_amdgcn_mfma_f32_16x16x32_bf16(
                    av[mf], bv[nf], acc[mf][nf], 0, 0, 0);
        __builtin_amdgcn_s_setprio(0);

        // ---- P3: kc=1, mf 4..7 ----
        av[0] = ds_read_b128_imm<16384 + 1024>(aAddr);
        av[1] = ds_read_b128_imm<16384 + 1280>(aAddr);
        av[2] = ds_read_b128_imm<16384 + 1536>(aAddr);
        av[3] = ds_read_b128_imm<16384 + 1792>(aAddr);
        if (pf) stageB(n + 1, 1);
        gate_lgkm0();
        __builtin_amdgcn_s_setprio(1);
#pragma unroll
        for (int mf = 0; mf < 4; ++mf)
#pragma unroll
            for (int nf = 0; nf < 4; ++nf)
                acc[4 + mf][nf] = __builtin_amdgcn_mfma_f32_16x16x32_bf16(
                    av[mf], bv[nf], acc[4 + mf][nf], 0, 0, 0);
        __builtin_amdgcn_s_setprio(0);
    }

    // epilogue: per-wave LDS transpose (stride 68 floats), coalesced stores.
    OutT* Cb = C + sC * bz + sSplit * sp;
    __syncthreads();   // full drain OK here (once per kernel)
    float* lws = (float*)(smem_raw) + (size_t)w * 1088;
    const int lr = lane >> 4;
    const int lc = lane & 15;
#pragma unroll
    for (int mf = 0; mf < 8; ++mf) {
#pragma unroll
        for (int nf = 0; nf < 4; ++nf)
#pragma unroll
            for (int v = 0; v < 4; ++v)
                lws[(q * 4 + v) * 68 + nf * 16 + col] = acc[mf][nf][v];
#pragma unroll
        for (int p = 0; p < 4; ++p) {
            f32x4 t = *(const f32x4*)&lws[(p * 4 + lr) * 68 + lc * 4];
            int row  = tileM + wm * 128 + mf * 16 + p * 4 + lr;
            int colg = tileN + wn * 64 + lc * 4;
            if constexpr (sizeof(OutT) == 2) {
                u16x4 u;
                u[0] = f2bf(t[0]); u[1] = f2bf(t[1]);
                u[2] = f2bf(t[2]); u[3] = f2bf(t[3]);
                *(u16x4*)&Cb[(size_t)row * ldc + colg] = u;
            } else {
                *(f32x4*)&Cb[(size_t)row * ldc + colg] = t;
            }
        }
        // per-wave epi slice is private; no inter-mf barrier needed
    }
}

extern "C" void kernel_launch(void* const* d_in, const int* in_sizes, int n_in,
                              void* d_out, int out_size, void* d_ws, size_t ws_size,
                              hipStream_t stream) {
    const float* X = (const float*)d_in[0];   // [4,4096,1024]
    const float* W = (const float*)d_in[1];   // [1024,1024]
    float* out = (float*)d_out;               // [4,4096,1024] fp32

    char* ws = (char*)d_ws;
    unsigned short* Xb = (unsigned short*)(ws);              // 33,554,432  [b][s][h]
    unsigned short* XT = (unsigned short*)(ws + 33554432);   // 33,554,432  [b][h][s]
    unsigned short* WT = (unsigned short*)(ws + 67108864);   //  2,097,152  [h'][o]
    unsigned short* G  = (unsigned short*)(ws + 69206016);   //  8,388,608  [b][o][h]
    unsigned short* MT = (unsigned short*)(ws + 77594624);   //  8,388,608  [b][h''][h]
    // Scratch (reused serially): Gpart then MTpart, each [sp(4)][b][1024][1024]
    unsigned short* Gpart  = (unsigned short*)(ws + 85983232); // 16,777,216
    unsigned short* MTpart = (unsigned short*)(ws + 85983232); // 16,777,216
    // high-water: 102,760,448 bytes < 153,092,096 proven available

    const size_t sBH = (size_t)B_DIM * H_DIM * H_DIM;

    // 1) casts + transposes
    cast_x_kernel<<<dim3(H_DIM / 64, S_DIM / 64, B_DIM), dim3(16, 16), 0, stream>>>(X, Xb, XT);
    cast_w_kernel<<<dim3(H_DIM / 32, H_DIM / 32, 1), dim3(32, 8), 0, stream>>>(W, WT);

    // 2) G_b = XT_b @ XT_b^T, full symmetric, split-K=4 (Ksub=1024, T=16).
    gemm_p7_kernel<unsigned short, 4><<<dim3(4, 4, B_DIM * 4), 512, 131072, stream>>>(
        XT, XT, Gpart, S_DIM, S_DIM, S_DIM, H_DIM,
        (size_t)H_DIM * S_DIM, (size_t)H_DIM * S_DIM, (size_t)H_DIM * H_DIM, sBH);
    reduce_cast_u16_kernel<4><<<dim3(sBH / 8 / 256), 256, 0, stream>>>(Gpart, G, sBH);

    // 3) MT_b = G_b @ WT^T, split-K=4 (Ksub=256, T=4)
    gemm_p7_kernel<unsigned short, 4><<<dim3(4, 4, B_DIM * 4), 512, 131072, stream>>>(
        G, WT, MTpart, H_DIM, H_DIM, H_DIM, H_DIM,
        (size_t)H_DIM * H_DIM, (size_t)0, (size_t)H_DIM * H_DIM, sBH);
    reduce_cast_u16_kernel<4><<<dim3(sBH / 8 / 256), 256, 0, stream>>>(MTpart, MT, sBH);

    // 4) att_b = Xb_b @ MT_b^T  [4096x1024], K=1024 (T=16), fp32 out.
    //    grid (16,4,4) = 256 blocks = 1/CU exactly.
    gemm_p7_kernel<float, 1><<<dim3(S_DIM / 256, H_DIM / 256, B_DIM), 512, 131072, stream>>>(
        Xb, MT, out, H_DIM, H_DIM, H_DIM, H_DIM,
        (size_t)S_DIM * H_DIM, (size_t)H_DIM * H_DIM, (size_t)S_DIM * H_DIM, 0);
}

// Round 8
// 227.996 us; speedup vs baseline: 1.2885x; 1.1139x over previous
//
#include <hip/hip_runtime.h>
#include <hip/hip_bf16.h>
#include <stdint.h>

#define H_DIM 1024
#define S_DIM 4096
#define B_DIM 4

typedef __bf16 bf16x8 __attribute__((ext_vector_type(8)));
typedef float f32x4 __attribute__((ext_vector_type(4)));
typedef unsigned short u16x4 __attribute__((ext_vector_type(4)));
typedef unsigned short u16x8 __attribute__((ext_vector_type(8)));

__device__ __forceinline__ unsigned short f2bf(float f) {
    union { float f; uint32_t u; } v; v.f = f;
    uint32_t u = v.u;
    uint32_t r = (u + 0x7FFFu + ((u >> 16) & 1u)) >> 16;  // round-to-nearest-even
    return (unsigned short)r;
}
__device__ __forceinline__ float bf2f(unsigned short u) {
    union { uint32_t u; float f; } v; v.u = (uint32_t)u << 16; return v.f;
}

// Clobber-free sync (R7): no "memory" clobber -> no compiler-inserted drains.
__device__ __forceinline__ void gate_vmcnt4() {
    __builtin_amdgcn_sched_barrier(0);
    asm volatile("s_waitcnt vmcnt(4)");
    __builtin_amdgcn_sched_barrier(0);
}
__device__ __forceinline__ void gate_vmcnt0() {
    __builtin_amdgcn_sched_barrier(0);
    asm volatile("s_waitcnt vmcnt(0)");
    __builtin_amdgcn_sched_barrier(0);
}
__device__ __forceinline__ void gate_lgkm0() {
    asm volatile("s_waitcnt lgkmcnt(0)");
    __builtin_amdgcn_sched_barrier(0);   // rule #18
}

template <int IMM>
__device__ __forceinline__ bf16x8 ds_read_b128_imm(unsigned addr) {
    bf16x8 r;
    asm volatile("ds_read_b128 %0, %1 offset:%2"
                 : "=v"(r) : "v"(addr), "i"(IMM));
    return r;
}

// X[b][s][h] fp32 -> Xb[b][s][h] bf16  and  XT[b][h][s] bf16 (vectorized)
__global__ __launch_bounds__(256)
void cast_x_kernel(const float* __restrict__ X,
                   unsigned short* __restrict__ Xb,
                   unsigned short* __restrict__ XT) {
    __shared__ float tile[64][65];
    const int b  = blockIdx.z;
    const int h0 = blockIdx.x * 64;
    const int s0 = blockIdx.y * 64;
    const int tx = threadIdx.x;   // 0..15
    const int ty = threadIdx.y;   // 0..15
#pragma unroll
    for (int j = 0; j < 4; ++j) {
        int s = ty + 16 * j;
        f32x4 v = *(const f32x4*)&X[((size_t)b * S_DIM + s0 + s) * H_DIM + h0 + tx * 4];
        u16x4 o;
#pragma unroll
        for (int k = 0; k < 4; ++k) {
            tile[s][tx * 4 + k] = v[k];
            o[k] = f2bf(v[k]);
        }
        *(u16x4*)&Xb[((size_t)b * S_DIM + s0 + s) * H_DIM + h0 + tx * 4] = o;
    }
    __syncthreads();
#pragma unroll
    for (int j = 0; j < 4; ++j) {
        int hh = ty + 16 * j;
        u16x4 o;
#pragma unroll
        for (int k = 0; k < 4; ++k)
            o[k] = f2bf(tile[tx * 4 + k][hh]);
        *(u16x4*)&XT[((size_t)b * H_DIM + h0 + hh) * S_DIM + s0 + tx * 4] = o;
    }
}

// W[o][h'] fp32 -> WT[h'][o] bf16 (small: 4 MB read)
__global__ void cast_w_kernel(const float* __restrict__ W,
                              unsigned short* __restrict__ WT) {
    __shared__ float tile[32][33];
    const int b0 = blockIdx.x * 32;
    const int o0 = blockIdx.y * 32;
    const int tx = threadIdx.x;
    const int ty = threadIdx.y;
#pragma unroll
    for (int i = 0; i < 4; ++i) {
        int o = ty + 8 * i;
        tile[o][tx] = W[(size_t)(o0 + o) * H_DIM + b0 + tx];
    }
    __syncthreads();
#pragma unroll
    for (int i = 0; i < 4; ++i) {
        int bb = ty + 8 * i;
        WT[(size_t)(b0 + bb) * H_DIM + o0 + tx] = f2bf(tile[tx][bb]);
    }
}

// Sum NSPLIT bf16 partials -> bf16. 16B/lane both directions.
template <int NSPLIT>
__global__ void reduce_cast_u16_kernel(const unsigned short* __restrict__ P,
                                       unsigned short* __restrict__ Out,
                                       size_t sSplit) {
    size_t i = ((size_t)blockIdx.x * blockDim.x + threadIdx.x) * 8;
    float s[8] = {0.f, 0.f, 0.f, 0.f, 0.f, 0.f, 0.f, 0.f};
#pragma unroll
    for (int sp = 0; sp < NSPLIT; ++sp) {
        u16x8 u = *(const u16x8*)&P[(size_t)sp * sSplit + i];
#pragma unroll
        for (int k = 0; k < 8; ++k) s[k] += bf2f(u[k]);
    }
    u16x8 o;
#pragma unroll
    for (int k = 0; k < 8; ++k) o[k] = f2bf(s[k]);
    *(u16x8*)&Out[i] = o;
}

// ============================================================================
// R8: COALESCED-STAGING GEMM. C[M,N] = A[M,K] @ Bt[N,K]^T.
//
// R0-R7 post-mortem: six schedule variants all ~22% MfmaUtil -> the limiter
// is a schedule-invariant resource. Found it: fragment-major LDS forced the
// global_load_lds source to stride lda between lanes -> each wave-instr hit
// 64 distinct 64B lines = 4096 line-transactions/K-tile/CU through TA (vs
// ~620 cyc MFMA). R8 changes ONLY the data layout (R7 schedule kept):
//
// LDS per operand: [kc(2)][row(256)][32k = 64B]. Staging wave-instr = 16
// rows x 64B: lane l -> row l>>2, k8-chunk (l&3)^((l>>3)&3) (slot perm).
// 4 consecutive lanes = one fully-used 64B line -> 16 lines/instr = the
// 1024-line/K-tile minimum (was 4096). LDS dest stays linear (rule #21:
// swizzle lives in the per-lane SOURCE address, m173 pattern).
// ds_read fragment (q,col): byte kc*16384 + row*64 + slot*16, slot =
// q^((col>>1)&3) — per-thread constant; the perm spreads every 16-lane
// subgroup over 8 distinct 4-bank sets (2-way = free, m136).
//
// Schedule per K-tile n (= R7, gates verified):
//   G0: vmcnt(4); s_barrier      [A(n,0),B(n,0) landed; (n,1) in flight]
//   P0: 8 ds_reads kc0 | stage A(n+1,0) | lgkm0 | prio1 16MFMA prio0
//   P1: 4 ds_reads kc0-hi | stage B(n+1,0) | lgkm0 | 16MFMA
//   G1: vmcnt(pf?4:0); s_barrier
//   P2/P3: kc1 mirror, staging A(n+1,1)/B(n+1,1)
// 2 loads/thread/stage-call -> same gate counts as R7. WAR: restage of buf
// (n+1)&1 only after G0/G1 barriers; all tile-(n-1) reads returned before
// each wave's own lgkm0 which precedes its barrier arrival.
// Requires M,N multiples of 256, T = Ksub/64 >= 1.
// ============================================================================
template <typename OutT, int NSPLIT>
__global__ __launch_bounds__(512, 2)
void gemm_c8_kernel(const unsigned short* __restrict__ A,
                    const unsigned short* __restrict__ Bt,
                    OutT* __restrict__ C,
                    int K, int lda, int ldb, int ldc,
                    size_t sA, size_t sB, size_t sC, size_t sSplit) {
    extern __shared__ char smem_raw[];
    // stage: [buf(2)][A 32KB | B 32KB] = 131072 B; epi overlays post-sync.

    const int tid  = threadIdx.x;
    const int w    = tid >> 6;       // 0..7
    const int lane = tid & 63;
    const int wm   = w & 1;          // M half: rows wm*128
    const int wn   = w >> 1;         // N quarter: cols wn*64
    const int q    = lane >> 4;      // 0..3 (k8 within kc-half)
    const int col  = lane & 15;

    const int tileM = blockIdx.x * 256;
    const int tileN = blockIdx.y * 256;
    const int bz   = blockIdx.z / NSPLIT;
    const int sp   = blockIdx.z % NSPLIT;
    const int Ksub = K / NSPLIT;
    const int T    = Ksub >> 6;      // K-tiles of 64

    const unsigned short* Ab = A + sA * bz + (size_t)sp * Ksub;
    const unsigned short* Bb = Bt + sB * bz + (size_t)sp * Ksub;

    auto lds3 = (__attribute__((address_space(3))) char*)&smem_raw[0];
    const unsigned ldsBase = (unsigned)(size_t)lds3;

    // fragment read bases. element (row,k=kc*32+q*8) at byte:
    //   buf*65536 + (op B: +32768) + kc*16384 + row*64 + slot*16,
    //   slot = q ^ ((row>>1)&3) = q ^ ((col>>1)&3)  (mf*8,wm*64,wn*32 ≡0 mod 4)
    const int slot = q ^ ((col >> 1) & 3);
    const unsigned aBase = ldsBase + (unsigned)(wm * 8192 + col * 64 + slot * 16);
    const unsigned bBase = ldsBase + 32768u + (unsigned)(wn * 4096 + col * 64 + slot * 16);
    // imm on top: kc*16384 + mf*1024 (A) / nf*1024 (B)   [max 23552 < 64K]

    // staging: wave w, unit j -> rowgroup g=2w+j (16 rows); lane l ->
    // row g*16 + (l>>2), fetched k8 = (l&3)^((l>>3)&3) (slot perm; (l>>3)&3 =
    // (row>>1)&3 since g*16 ≡ 0 mod 8). 4-lane groups read one 64B line.
    const int lrow = lane >> 2;
    const int koff = ((lane & 3) ^ ((lane >> 3) & 3)) * 8;
    const unsigned short* pA[2];
    const unsigned short* pB[2];
    unsigned dstR[2];
#pragma unroll
    for (int j = 0; j < 2; ++j) {
        int g = 2 * w + j;
        pA[j] = Ab + (size_t)(tileM + g * 16 + lrow) * lda + koff;
        pB[j] = Bb + (size_t)(tileN + g * 16 + lrow) * ldb + koff;
        dstR[j] = (unsigned)(g * 1024);   // wave-uniform LDS row-group base
    }
    // stage kc-half h of tile tgt into buf tgt&1 (2 loads/thread)
    auto stageA = [&](int tgt, int h) {
#pragma unroll
        for (int j = 0; j < 2; ++j)
            __builtin_amdgcn_global_load_lds(
                (const __attribute__((address_space(1))) void*)(pA[j] + tgt * 64 + h * 32),
                (__attribute__((address_space(3))) void*)(lds3 + ((unsigned)(tgt & 1) * 65536u + (unsigned)h * 16384u + dstR[j])),
                16, 0, 0);
    };
    auto stageB = [&](int tgt, int h) {
#pragma unroll
        for (int j = 0; j < 2; ++j)
            __builtin_amdgcn_global_load_lds(
                (const __attribute__((address_space(1))) void*)(pB[j] + tgt * 64 + h * 32),
                (__attribute__((address_space(3))) void*)(lds3 + ((unsigned)(tgt & 1) * 65536u + 32768u + (unsigned)h * 16384u + dstR[j])),
                16, 0, 0);
    };

    f32x4 acc[8][4];
#pragma unroll
    for (int r = 0; r < 8; ++r)
#pragma unroll
        for (int c = 0; c < 4; ++c)
            acc[r][c] = (f32x4){0.f, 0.f, 0.f, 0.f};

    // prologue: tile 0's 4 halves, consumption order A0,B0,A1,B1
    stageA(0, 0); stageB(0, 0); stageA(0, 1); stageB(0, 1);

    for (int n = 0; n < T; ++n) {
        const unsigned aAddr = aBase + (unsigned)((n & 1) << 16);
        const unsigned bAddr = bBase + (unsigned)((n & 1) << 16);
        const bool pf = (n + 1 < T);
        bf16x8 av[4], bv[4];

        // ===== G0 =====
        gate_vmcnt4();
        __builtin_amdgcn_s_barrier();

        // ---- P0: kc=0, mf 0..3 ----
        av[0] = ds_read_b128_imm<0>(aAddr);
        av[1] = ds_read_b128_imm<1024>(aAddr);
        av[2] = ds_read_b128_imm<2048>(aAddr);
        av[3] = ds_read_b128_imm<3072>(aAddr);
        bv[0] = ds_read_b128_imm<0>(bAddr);
        bv[1] = ds_read_b128_imm<1024>(bAddr);
        bv[2] = ds_read_b128_imm<2048>(bAddr);
        bv[3] = ds_read_b128_imm<3072>(bAddr);
        if (pf) stageA(n + 1, 0);
        gate_lgkm0();
        __builtin_amdgcn_s_setprio(1);
#pragma unroll
        for (int mf = 0; mf < 4; ++mf)
#pragma unroll
            for (int nf = 0; nf < 4; ++nf)
                acc[mf][nf] = __builtin_amdgcn_mfma_f32_16x16x32_bf16(
                    av[mf], bv[nf], acc[mf][nf], 0, 0, 0);
        __builtin_amdgcn_s_setprio(0);

        // ---- P1: kc=0, mf 4..7 (bv reused) ----
        av[0] = ds_read_b128_imm<4096>(aAddr);
        av[1] = ds_read_b128_imm<5120>(aAddr);
        av[2] = ds_read_b128_imm<6144>(aAddr);
        av[3] = ds_read_b128_imm<7168>(aAddr);
        if (pf) stageB(n + 1, 0);
        gate_lgkm0();
        __builtin_amdgcn_s_setprio(1);
#pragma unroll
        for (int mf = 0; mf < 4; ++mf)
#pragma unroll
            for (int nf = 0; nf < 4; ++nf)
                acc[4 + mf][nf] = __builtin_amdgcn_mfma_f32_16x16x32_bf16(
                    av[mf], bv[nf], acc[4 + mf][nf], 0, 0, 0);
        __builtin_amdgcn_s_setprio(0);

        // ===== G1 =====
        if (pf) gate_vmcnt4();
        else    gate_vmcnt0();
        __builtin_amdgcn_s_barrier();

        // ---- P2: kc=1, mf 0..3, new bv ----
        av[0] = ds_read_b128_imm<16384 + 0>(aAddr);
        av[1] = ds_read_b128_imm<16384 + 1024>(aAddr);
        av[2] = ds_read_b128_imm<16384 + 2048>(aAddr);
        av[3] = ds_read_b128_imm<16384 + 3072>(aAddr);
        bv[0] = ds_read_b128_imm<16384 + 0>(bAddr);
        bv[1] = ds_read_b128_imm<16384 + 1024>(bAddr);
        bv[2] = ds_read_b128_imm<16384 + 2048>(bAddr);
        bv[3] = ds_read_b128_imm<16384 + 3072>(bAddr);
        if (pf) stageA(n + 1, 1);
        gate_lgkm0();
        __builtin_amdgcn_s_setprio(1);
#pragma unroll
        for (int mf = 0; mf < 4; ++mf)
#pragma unroll
            for (int nf = 0; nf < 4; ++nf)
                acc[mf][nf] = __builtin_amdgcn_mfma_f32_16x16x32_bf16(
                    av[mf], bv[nf], acc[mf][nf], 0, 0, 0);
        __builtin_amdgcn_s_setprio(0);

        // ---- P3: kc=1, mf 4..7 ----
        av[0] = ds_read_b128_imm<16384 + 4096>(aAddr);
        av[1] = ds_read_b128_imm<16384 + 5120>(aAddr);
        av[2] = ds_read_b128_imm<16384 + 6144>(aAddr);
        av[3] = ds_read_b128_imm<16384 + 7168>(aAddr);
        if (pf) stageB(n + 1, 1);
        gate_lgkm0();
        __builtin_amdgcn_s_setprio(1);
#pragma unroll
        for (int mf = 0; mf < 4; ++mf)
#pragma unroll
            for (int nf = 0; nf < 4; ++nf)
                acc[4 + mf][nf] = __builtin_amdgcn_mfma_f32_16x16x32_bf16(
                    av[mf], bv[nf], acc[4 + mf][nf], 0, 0, 0);
        __builtin_amdgcn_s_setprio(0);
    }

    // epilogue: per-wave LDS transpose (stride 68 floats), coalesced stores.
    OutT* Cb = C + sC * bz + sSplit * sp;
    __syncthreads();   // full drain OK here (once per kernel)
    float* lws = (float*)(smem_raw) + (size_t)w * 1088;
    const int lr = lane >> 4;
    const int lc = lane & 15;
#pragma unroll
    for (int mf = 0; mf < 8; ++mf) {
#pragma unroll
        for (int nf = 0; nf < 4; ++nf)
#pragma unroll
            for (int v = 0; v < 4; ++v)
                lws[(q * 4 + v) * 68 + nf * 16 + col] = acc[mf][nf][v];
#pragma unroll
        for (int p = 0; p < 4; ++p) {
            f32x4 t = *(const f32x4*)&lws[(p * 4 + lr) * 68 + lc * 4];
            int row  = tileM + wm * 128 + mf * 16 + p * 4 + lr;
            int colg = tileN + wn * 64 + lc * 4;
            if constexpr (sizeof(OutT) == 2) {
                u16x4 u;
                u[0] = f2bf(t[0]); u[1] = f2bf(t[1]);
                u[2] = f2bf(t[2]); u[3] = f2bf(t[3]);
                *(u16x4*)&Cb[(size_t)row * ldc + colg] = u;
            } else {
                *(f32x4*)&Cb[(size_t)row * ldc + colg] = t;
            }
        }
        // per-wave epi slice is private; no inter-mf barrier needed
    }
}

extern "C" void kernel_launch(void* const* d_in, const int* in_sizes, int n_in,
                              void* d_out, int out_size, void* d_ws, size_t ws_size,
                              hipStream_t stream) {
    const float* X = (const float*)d_in[0];   // [4,4096,1024]
    const float* W = (const float*)d_in[1];   // [1024,1024]
    float* out = (float*)d_out;               // [4,4096,1024] fp32

    char* ws = (char*)d_ws;
    unsigned short* Xb = (unsigned short*)(ws);              // 33,554,432  [b][s][h]
    unsigned short* XT = (unsigned short*)(ws + 33554432);   // 33,554,432  [b][h][s]
    unsigned short* WT = (unsigned short*)(ws + 67108864);   //  2,097,152  [h'][o]
    unsigned short* G  = (unsigned short*)(ws + 69206016);   //  8,388,608  [b][o][h]
    unsigned short* MT = (unsigned short*)(ws + 77594624);   //  8,388,608  [b][h''][h]
    // Scratch (reused serially): Gpart then MTpart, each [sp(4)][b][1024][1024]
    unsigned short* Gpart  = (unsigned short*)(ws + 85983232); // 16,777,216
    unsigned short* MTpart = (unsigned short*)(ws + 85983232); // 16,777,216
    // high-water: 102,760,448 bytes < 153,092,096 proven available

    const size_t sBH = (size_t)B_DIM * H_DIM * H_DIM;

    // 1) casts + transposes
    cast_x_kernel<<<dim3(H_DIM / 64, S_DIM / 64, B_DIM), dim3(16, 16), 0, stream>>>(X, Xb, XT);
    cast_w_kernel<<<dim3(H_DIM / 32, H_DIM / 32, 1), dim3(32, 8), 0, stream>>>(W, WT);

    // 2) G_b = XT_b @ XT_b^T, full symmetric, split-K=4 (Ksub=1024, T=16).
    gemm_c8_kernel<unsigned short, 4><<<dim3(4, 4, B_DIM * 4), 512, 131072, stream>>>(
        XT, XT, Gpart, S_DIM, S_DIM, S_DIM, H_DIM,
        (size_t)H_DIM * S_DIM, (size_t)H_DIM * S_DIM, (size_t)H_DIM * H_DIM, sBH);
    reduce_cast_u16_kernel<4><<<dim3(sBH / 8 / 256), 256, 0, stream>>>(Gpart, G, sBH);

    // 3) MT_b = G_b @ WT^T, split-K=4 (Ksub=256, T=4)
    gemm_c8_kernel<unsigned short, 4><<<dim3(4, 4, B_DIM * 4), 512, 131072, stream>>>(
        G, WT, MTpart, H_DIM, H_DIM, H_DIM, H_DIM,
        (size_t)H_DIM * H_DIM, (size_t)0, (size_t)H_DIM * H_DIM, sBH);
    reduce_cast_u16_kernel<4><<<dim3(sBH / 8 / 256), 256, 0, stream>>>(MTpart, MT, sBH);

    // 4) att_b = Xb_b @ MT_b^T  [4096x1024], K=1024 (T=16), fp32 out.
    //    grid (16,4,4) = 256 blocks = 1/CU exactly.
    gemm_c8_kernel<float, 1><<<dim3(S_DIM / 256, H_DIM / 256, B_DIM), 512, 131072, stream>>>(
        Xb, MT, out, H_DIM, H_DIM, H_DIM, H_DIM,
        (size_t)S_DIM * H_DIM, (size_t)H_DIM * H_DIM, (size_t)S_DIM * H_DIM, 0);
}